// Round 2
// baseline (79.206 us; speedup 1.0000x reference)
//
#include <hip/hip_runtime.h>

// TripletLoss with per-class margins.
// d_ap = ||a - p + 1e-6||_2, d_an = ||a - n + 1e-6||_2
// loss = mean(relu(d_ap - d_an + margin[cs]))
//
// Round 1 restructure: 16 lanes per row, 2 x float4 per lane per array,
// 2 rows unrolled per group-iteration -> 12 independent 16B loads in flight
// per thread, shuffle depth 4 (masks 1,2,4,8), 4 interleaved shuffle chains.

#define TL_D 128
#define TL_BLOCK 256
#define TL_MAXBLOCKS 2048
#define TL_LPR 16   // lanes per row

__device__ __forceinline__ float tl_margin(int c) {
    return (c == 0) ? 0.10f
         : (c == 1) ? 0.085f
         : (c == 2) ? 0.07f
         : 0.04f;
}

#define TL_ACC(av, bv, dst)                         \
    {                                               \
        float _d;                                   \
        _d = (av).x - (bv).x + 1e-6f; dst += _d * _d; \
        _d = (av).y - (bv).y + 1e-6f; dst += _d * _d; \
        _d = (av).z - (bv).z + 1e-6f; dst += _d * _d; \
        _d = (av).w - (bv).w + 1e-6f; dst += _d * _d; \
    }

__global__ __launch_bounds__(TL_BLOCK) void triplet_partial_kernel(
    const float* __restrict__ a,
    const float* __restrict__ p,
    const float* __restrict__ n,
    const int* __restrict__ cs32,   // low 32-bit words of the int64 cs array
    float* __restrict__ partials,
    int nrows)
{
    const int tid  = threadIdx.x;
    const int lane = tid & (TL_LPR - 1);
    const int gib  = tid >> 4;                          // 16 groups / 256-block
    const int G    = blockIdx.x * (TL_BLOCK / TL_LPR) + gib;
    const int TG   = gridDim.x * (TL_BLOCK / TL_LPR);

    const int e0 = lane * 4;        // first float4 of this lane's slice
    const int e1 = lane * 4 + 64;   // second float4 (second half of the row)

    float local = 0.0f;

    for (int base = 2 * G; base < nrows; base += 2 * TG) {
        const int r0 = base;
        const bool have1 = (base + 1) < nrows;
        const int r1 = have1 ? (base + 1) : base;

        const float* a0 = a + (size_t)r0 * TL_D;
        const float* p0 = p + (size_t)r0 * TL_D;
        const float* n0 = n + (size_t)r0 * TL_D;
        const float* a1 = a + (size_t)r1 * TL_D;
        const float* p1 = p + (size_t)r1 * TL_D;
        const float* n1 = n + (size_t)r1 * TL_D;

        // 12 independent 16B loads — issue them all before dependent compute.
        const float4 aA = *reinterpret_cast<const float4*>(a0 + e0);
        const float4 aB = *reinterpret_cast<const float4*>(a0 + e1);
        const float4 pA = *reinterpret_cast<const float4*>(p0 + e0);
        const float4 pB = *reinterpret_cast<const float4*>(p0 + e1);
        const float4 nA = *reinterpret_cast<const float4*>(n0 + e0);
        const float4 nB = *reinterpret_cast<const float4*>(n0 + e1);
        const float4 aC = *reinterpret_cast<const float4*>(a1 + e0);
        const float4 aD = *reinterpret_cast<const float4*>(a1 + e1);
        const float4 pC = *reinterpret_cast<const float4*>(p1 + e0);
        const float4 pD = *reinterpret_cast<const float4*>(p1 + e1);
        const float4 nC = *reinterpret_cast<const float4*>(n1 + e0);
        const float4 nD = *reinterpret_cast<const float4*>(n1 + e1);

        float dap0 = 0.0f, dan0 = 0.0f, dap1 = 0.0f, dan1 = 0.0f;
        TL_ACC(aA, pA, dap0); TL_ACC(aB, pB, dap0);
        TL_ACC(aA, nA, dan0); TL_ACC(aB, nB, dan0);
        TL_ACC(aC, pC, dap1); TL_ACC(aD, pD, dap1);
        TL_ACC(aC, nC, dan1); TL_ACC(aD, nD, dan1);

        // Butterfly reduce within each 16-lane group; 4 independent chains.
        #pragma unroll
        for (int m = 1; m <= 8; m <<= 1) {
            dap0 += __shfl_xor(dap0, m, 64);
            dan0 += __shfl_xor(dan0, m, 64);
            dap1 += __shfl_xor(dap1, m, 64);
            dan1 += __shfl_xor(dan1, m, 64);
        }

        if (lane == 0) {
            const int c0 = cs32[2 * r0];
            const float l0 = sqrtf(dap0) - sqrtf(dan0) + tl_margin(c0);
            local += fmaxf(l0, 0.0f);
            if (have1) {
                const int c1 = cs32[2 * r1];
                const float l1 = sqrtf(dap1) - sqrtf(dan1) + tl_margin(c1);
                local += fmaxf(l1, 0.0f);
            }
        }
    }

    // Block-level reduction of per-thread locals.
    __shared__ float sdata[TL_BLOCK];
    sdata[tid] = local;
    __syncthreads();
    #pragma unroll
    for (int s = TL_BLOCK / 2; s > 0; s >>= 1) {
        if (tid < s) sdata[tid] += sdata[tid + s];
        __syncthreads();
    }
    if (tid == 0) partials[blockIdx.x] = sdata[0];
}

__global__ __launch_bounds__(TL_BLOCK) void triplet_final_kernel(
    const float* __restrict__ partials,
    int nparts,
    float* __restrict__ out,
    float invB)
{
    __shared__ float sdata[TL_BLOCK];
    float local = 0.0f;
    for (int i = threadIdx.x; i < nparts; i += TL_BLOCK) local += partials[i];
    sdata[threadIdx.x] = local;
    __syncthreads();
    #pragma unroll
    for (int s = TL_BLOCK / 2; s > 0; s >>= 1) {
        if (threadIdx.x < s) sdata[threadIdx.x] += sdata[threadIdx.x + s];
        __syncthreads();
    }
    if (threadIdx.x == 0) out[0] = sdata[0] * invB;
}

extern "C" void kernel_launch(void* const* d_in, const int* in_sizes, int n_in,
                              void* d_out, int out_size, void* d_ws, size_t ws_size,
                              hipStream_t stream)
{
    const float* a    = (const float*)d_in[0];
    const float* p    = (const float*)d_in[1];
    const float* n    = (const float*)d_in[2];
    const int*   cs32 = (const int*)d_in[3];   // int64 cs, values 0..3 -> low words
    float*       out  = (float*)d_out;
    float*       partials = (float*)d_ws;

    const int nrows = in_sizes[3];  // B = 262144 (cs element count)

    int nblocks = TL_MAXBLOCKS;
    const int maxParts = (int)(ws_size / sizeof(float));
    if (nblocks > maxParts) nblocks = maxParts;
    if (nblocks < 1) nblocks = 1;

    triplet_partial_kernel<<<nblocks, TL_BLOCK, 0, stream>>>(a, p, n, cs32, partials, nrows);
    triplet_final_kernel<<<1, TL_BLOCK, 0, stream>>>(partials, nblocks, out, 1.0f / (float)nrows);
}

// Round 3
// 76.522 us; speedup vs baseline: 1.0351x; 1.0351x over previous
//
#include <hip/hip_runtime.h>

// TripletLoss with per-class margins.
// d_ap = ||a - p + 1e-6||_2, d_an = ||a - n + 1e-6||_2
// loss = mean(relu(d_ap - d_an + margin[cs]))
//
// Round 2: R0 structure (32 lanes/row, 2 rows/wave/iter, 16 iterations)
// + depth-1 software prefetch so next iteration's loads are in flight
// during the shuffle-reduce chain. Branch-free clamped prefetch row.
// Lightweight block reduce (1 barrier).

#define TL_D 128
#define TL_BLOCK 256
#define TL_GRID 2048

__device__ __forceinline__ float tl_margin(int c) {
    return (c == 0) ? 0.10f
         : (c == 1) ? 0.085f
         : (c == 2) ? 0.07f
         : 0.04f;
}

#define TL_ACC(av, bv, dst)                           \
    {                                                 \
        float _d;                                     \
        _d = (av).x - (bv).x + 1e-6f; dst += _d * _d; \
        _d = (av).y - (bv).y + 1e-6f; dst += _d * _d; \
        _d = (av).z - (bv).z + 1e-6f; dst += _d * _d; \
        _d = (av).w - (bv).w + 1e-6f; dst += _d * _d; \
    }

__global__ __launch_bounds__(TL_BLOCK) void triplet_partial_kernel(
    const float* __restrict__ a,
    const float* __restrict__ p,
    const float* __restrict__ n,
    const int* __restrict__ cs32,   // low 32-bit words of the int64 cs array
    float* __restrict__ partials,
    int nrows)
{
    const int tid    = threadIdx.x;
    const int lane32 = tid & 31;
    const int G      = blockIdx.x * (TL_BLOCK / 32) + (tid >> 5);
    const int TG     = gridDim.x * (TL_BLOCK / 32);

    float local = 0.0f;

    int row = G;
    float4 aC, pC, nC;
    int cC = 0;
    if (row < nrows) {
        const size_t base = (size_t)row * TL_D + lane32 * 4;
        aC = *reinterpret_cast<const float4*>(a + base);
        pC = *reinterpret_cast<const float4*>(p + base);
        nC = *reinterpret_cast<const float4*>(n + base);
        cC = cs32[2 * (size_t)row];
    }

    while (row < nrows) {
        // ---- prefetch next iteration (branch-free, clamped row) ----
        const int nrow = row + TG;
        const int lrow = (nrow < nrows) ? nrow : row;   // stays in bounds
        const size_t nb = (size_t)lrow * TL_D + lane32 * 4;
        const float4 aN = *reinterpret_cast<const float4*>(a + nb);
        const float4 pN = *reinterpret_cast<const float4*>(p + nb);
        const float4 nN = *reinterpret_cast<const float4*>(n + nb);
        const int    cN = cs32[2 * (size_t)lrow];

        // ---- compute current iteration ----
        float dap = 0.0f, dan = 0.0f;
        TL_ACC(aC, pC, dap);
        TL_ACC(aC, nC, dan);

        // Butterfly reduce across the 32 lanes of this group.
        #pragma unroll
        for (int m = 1; m <= 16; m <<= 1) {
            dap += __shfl_xor(dap, m, 64);
            dan += __shfl_xor(dan, m, 64);
        }

        if (lane32 == 0) {
            local += fmaxf(sqrtf(dap) - sqrtf(dan) + tl_margin(cC), 0.0f);
        }

        // ---- rotate (compiler places vmcnt wait here, after shuffles) ----
        row = nrow;
        aC = aN; pC = pN; nC = nN; cC = cN;
    }

    // Cross-group combine within the wave (only lanes 0 and 32 are nonzero).
    local += __shfl_xor(local, 32, 64);

    __shared__ float swave[TL_BLOCK / 64];
    if ((tid & 63) == 0) swave[tid >> 6] = local;
    __syncthreads();
    if (tid == 0) {
        float s = 0.0f;
        #pragma unroll
        for (int w = 0; w < TL_BLOCK / 64; ++w) s += swave[w];
        partials[blockIdx.x] = s;
    }
}

__global__ __launch_bounds__(TL_BLOCK) void triplet_final_kernel(
    const float* __restrict__ partials,
    int nparts,
    float* __restrict__ out,
    float invB)
{
    __shared__ float sdata[TL_BLOCK];
    float local = 0.0f;
    for (int i = threadIdx.x; i < nparts; i += TL_BLOCK) local += partials[i];
    sdata[threadIdx.x] = local;
    __syncthreads();
    #pragma unroll
    for (int s = TL_BLOCK / 2; s > 0; s >>= 1) {
        if (threadIdx.x < s) sdata[threadIdx.x] += sdata[threadIdx.x + s];
        __syncthreads();
    }
    if (threadIdx.x == 0) out[0] = sdata[0] * invB;
}

extern "C" void kernel_launch(void* const* d_in, const int* in_sizes, int n_in,
                              void* d_out, int out_size, void* d_ws, size_t ws_size,
                              hipStream_t stream)
{
    const float* a    = (const float*)d_in[0];
    const float* p    = (const float*)d_in[1];
    const float* n    = (const float*)d_in[2];
    const int*   cs32 = (const int*)d_in[3];   // int64 cs, values 0..3 -> low words
    float*       out  = (float*)d_out;
    float*       partials = (float*)d_ws;

    const int nrows = in_sizes[3];  // B = 262144 (cs element count)

    int nblocks = TL_GRID;
    const int maxParts = (int)(ws_size / sizeof(float));
    if (nblocks > maxParts) nblocks = maxParts;
    if (nblocks < 1) nblocks = 1;

    triplet_partial_kernel<<<nblocks, TL_BLOCK, 0, stream>>>(a, p, n, cs32, partials, nrows);
    triplet_final_kernel<<<1, TL_BLOCK, 0, stream>>>(partials, nblocks, out, 1.0f / (float)nrows);
}